// Round 1
// 1126.459 us; speedup vs baseline: 1.3907x; 1.3907x over previous
//
#include <hip/hip_runtime.h>
#include <hip/hip_bf16.h>
#include <stdint.h>

// FATAttention: B=16, T=512, D=256, H=8, E=32, BASIS=8, 20 sinkhorn iters.
// R7: k3 rebuilt again. R6's premise (156KB LDS -> 1 blk/CU -> compiler
// targets 1 wave/SIMD -> 512-reg budget) was FALSE: dynamic LDS is invisible
// at compile time; rocprof showed VGPR_Count=256 vs ~390 needed -> ~140
// dwords/thread spilled and re-read in all 40 serial iterations, 1 wave/SIMD,
// VALUBusy 4.6%. New k3: 1024 thr/block (4 waves/SIMD), half-row per thread
// (92 reg dwords + 36 LDS dwords), __launch_bounds__(1024,4) -> 128-reg cap
// with ~115 demand -> no spill, latency hidden.

#define B_  16
#define T_  512
#define D_  256
#define H_  8
#define E_  32
#define HE_ 256
#define KB_ 8
#define HB_ 128

typedef unsigned short u16;
typedef __attribute__((ext_vector_type(8))) short short8;
typedef __attribute__((ext_vector_type(4))) float floatx4;

__device__ __forceinline__ float bflo(uint32_t u){ return __uint_as_float(u << 16); }
__device__ __forceinline__ float bfhi(uint32_t u){ return __uint_as_float(u & 0xffff0000u); }
__device__ __forceinline__ u16 f2bf(float f){ // RTNE
  uint32_t u = __float_as_uint(f);
  return (u16)((u + 0x7fffu + ((u >> 16) & 1u)) >> 16);
}
__device__ __forceinline__ uint32_t pk2(float a, float b){
  return (uint32_t)f2bf(a) | ((uint32_t)f2bf(b) << 16);
}

// ---------------------------------------------------------------- Kcvt: X->bf16
__global__ void __launch_bounds__(256)
kcvt_x(const float* __restrict__ X, u16* __restrict__ Xb){
  int idx = (blockIdx.x*256 + threadIdx.x)*4;
  float4 v = *(const float4*)(X + idx);
  uint2 o; o.x = pk2(v.x, v.y); o.y = pk2(v.z, v.w);
  *(uint2*)(Xb + idx) = o;
}

// ---------------------------------------------------------------- KT: basis^T
// Q_basis/K_basis [k][d][e] fp32 -> QbT/KbT [k][e][d] bf16
__global__ void __launch_bounds__(256)
kT_basis(const float* __restrict__ Qb, const float* __restrict__ Kb,
         u16* __restrict__ QbT, u16* __restrict__ KbT){
  __shared__ float tile[64][65];
  int slot = blockIdx.y;     // 0..15
  const float* src = (slot < 8) ? Qb + (size_t)slot*D_*HE_ : Kb + (size_t)(slot-8)*D_*HE_;
  u16*         dst = (slot < 8) ? QbT + (size_t)slot*HE_*D_ : KbT + (size_t)(slot-8)*HE_*D_;
  int ti = blockIdx.x >> 2, tj = blockIdx.x & 3;   // d-tile, e-tile
  int tid = threadIdx.x;
  #pragma unroll
  for (int i = 0; i < 16; ++i){
    int idx = tid + 256*i;
    int rr = idx >> 6, cc = idx & 63;
    tile[rr][cc] = src[(size_t)(ti*64 + rr)*HE_ + tj*64 + cc];
  }
  __syncthreads();
  #pragma unroll
  for (int i = 0; i < 16; ++i){
    int idx = tid + 256*i;
    int rr = idx >> 6, cc = idx & 63;
    dst[(size_t)(tj*64 + rr)*D_ + ti*64 + cc] = f2bf(tile[cc][rr]);
  }
}

// ---------------------------------------------------------------- K0: meta
__global__ void k0_meta(const float* __restrict__ te, const float* __restrict__ wq,
                        const float* __restrict__ wk, float* __restrict__ qw,
                        float* __restrict__ kw){
  int t = blockIdx.x;
  int lane = threadIdx.x;        // 64
  int k = lane >> 3, part = lane & 7;
  const float* ta = te + t*D_ + part*32;
  const float* qa = wq + (t*KB_ + k)*D_ + part*32;
  const float* ka = wk + (t*KB_ + k)*D_ + part*32;
  float sq = 0.f, sk = 0.f;
  #pragma unroll
  for (int i = 0; i < 8; ++i){
    float4 a = ((const float4*)ta)[i];
    float4 b = ((const float4*)qa)[i];
    float4 c = ((const float4*)ka)[i];
    sq += a.x*b.x + a.y*b.y + a.z*b.z + a.w*b.w;
    sk += a.x*c.x + a.y*c.y + a.z*c.z + a.w*c.w;
  }
  sq += __shfl_down(sq, 4, 8); sq += __shfl_down(sq, 2, 8); sq += __shfl_down(sq, 1, 8);
  sk += __shfl_down(sk, 4, 8); sk += __shfl_down(sk, 2, 8); sk += __shfl_down(sk, 1, 8);
  if (part == 0){
    qw[t*KB_ + k] = sq * 0.17677669529663687f;  // fold 1/sqrt(32) into q path
    kw[t*KB_ + k] = sk;
  }
}

// -------------------------------------------------------------- Kpre
// lA = sigmoid(L)*0.5*(A+A^T) bf16;  oml = 1-sigmoid(L) bf16
__global__ void __launch_bounds__(256)
k_pre(const float* __restrict__ A, const float* __restrict__ L,
      u16* __restrict__ lA, u16* __restrict__ oml){
  __shared__ float tile[64][65];
  int I = blockIdx.x >> 3, J = blockIdx.x & 7;
  int tid = threadIdx.x;
  #pragma unroll
  for (int i = 0; i < 16; ++i){
    int idx = tid + 256*i;
    int rr = idx >> 6, cc = idx & 63;
    tile[rr][cc] = A[(J*64 + rr)*T_ + I*64 + cc];
  }
  __syncthreads();
  #pragma unroll
  for (int i = 0; i < 16; ++i){
    int idx = tid + 256*i;
    int rr = idx >> 6, cc = idx & 63;
    int t = I*64 + rr, s = J*64 + cc;
    float lamv = 1.0f / (1.0f + __expf(-L[t*T_ + s]));
    float asym = 0.5f*(A[t*T_ + s] + tile[cc][rr]);
    lA[t*T_ + s]  = f2bf(lamv*asym);
    oml[t*T_ + s] = f2bf(1.0f - lamv);
  }
}

// ---------------------------------------------------------------- K1a: Y GEMMs
// Y[kb][bt][e] = Xb[bt][:] . basis[kb][:][e]   (8 GEMMs [8192,256]@[256,256])
__global__ void __launch_bounds__(256)
k1a_gemm(const u16* __restrict__ Xb, const u16* __restrict__ BT, u16* __restrict__ Y){
  __shared__ u16 At[128*40];
  __shared__ u16 Bt[128*40];
  int bt0 = blockIdx.x*128;
  int j   = blockIdx.y;        // e-half
  int kb  = blockIdx.z;
  const u16* Bsrc = BT + (size_t)kb*HE_*D_;
  int tid = threadIdx.x, lane = tid & 63, w = tid >> 6;
  int q_l = lane >> 4, c_l = lane & 15;
  int srow = tid >> 2, sch = (tid & 3)*8;
  floatx4 acc[2][8];
  #pragma unroll
  for (int mt = 0; mt < 2; ++mt)
    #pragma unroll
    for (int n = 0; n < 8; ++n) acc[mt][n] = (floatx4){0,0,0,0};

  #pragma unroll 1
  for (int ks = 0; ks < 8; ++ks){
    int k0 = ks*32;
    if (ks) __syncthreads();
    *(short8*)&At[srow*40 + sch] = *(const short8*)&Xb[(size_t)(bt0 + srow)*D_ + k0 + sch];
    *(short8*)&Bt[srow*40 + sch] = *(const short8*)&Bsrc[(size_t)(j*128 + srow)*D_ + k0 + sch];
    __syncthreads();
    short8 a0 = *(const short8*)&At[(w*32 +  0 + c_l)*40 + q_l*8];
    short8 a1 = *(const short8*)&At[(w*32 + 16 + c_l)*40 + q_l*8];
    #pragma unroll
    for (int n = 0; n < 8; ++n){
      short8 bfr = *(const short8*)&Bt[(n*16 + c_l)*40 + q_l*8];
      acc[0][n] = __builtin_amdgcn_mfma_f32_16x16x32_bf16(a0, bfr, acc[0][n], 0, 0, 0);
      acc[1][n] = __builtin_amdgcn_mfma_f32_16x16x32_bf16(a1, bfr, acc[1][n], 0, 0, 0);
    }
  }
  #pragma unroll
  for (int mt = 0; mt < 2; ++mt)
    #pragma unroll
    for (int n = 0; n < 8; ++n)
      #pragma unroll
      for (int r = 0; r < 4; ++r){
        int row = w*32 + mt*16 + q_l*4 + r;
        int e = j*128 + n*16 + c_l;
        Y[((size_t)kb << 21) + (size_t)(bt0 + row)*HE_ + e] = f2bf(acc[mt][n][r]);
      }
}

// ---------------------------------------------------------------- K1b: mix
// dst[h][b][t][e&31] = sum_k wv[t,k] * Y[k][b*T+t][e]
__global__ void __launch_bounds__(256)
k1b_mix(const u16* __restrict__ Y, const float* __restrict__ wv, u16* __restrict__ dst){
  int tid = threadIdx.x;
  int row = blockIdx.x*16 + (tid >> 4);
  int e0 = (tid & 15)*16;
  int b = row >> 9, t = row & 511;
  float w8[8];
  #pragma unroll
  for (int k = 0; k < 8; ++k) w8[k] = wv[t*8 + k];
  float acc[16];
  #pragma unroll
  for (int i = 0; i < 16; ++i) acc[i] = 0.f;
  #pragma unroll
  for (int k = 0; k < 8; ++k){
    const u16* yp = Y + ((size_t)k << 21) + (size_t)row*HE_ + e0;
    uint4 v0 = *(const uint4*)yp;
    uint4 v1 = *(const uint4*)(yp + 8);
    uint32_t vv[8] = {v0.x,v0.y,v0.z,v0.w,v1.x,v1.y,v1.z,v1.w};
    float wk = w8[k];
    #pragma unroll
    for (int d = 0; d < 8; ++d){
      acc[2*d]   += wk*bflo(vv[d]);
      acc[2*d+1] += wk*bfhi(vv[d]);
    }
  }
  uint4 o0, o1;
  o0.x = pk2(acc[0],acc[1]);   o0.y = pk2(acc[2],acc[3]);
  o0.z = pk2(acc[4],acc[5]);   o0.w = pk2(acc[6],acc[7]);
  o1.x = pk2(acc[8],acc[9]);   o1.y = pk2(acc[10],acc[11]);
  o1.z = pk2(acc[12],acc[13]); o1.w = pk2(acc[14],acc[15]);
  int h = e0 >> 5, off = e0 & 31;
  u16* dp = dst + (((size_t)(h*16 + b)*T_ + t)*E_ + off);
  *(uint4*)dp = o0;
  *(uint4*)(dp + 8) = o1;
}

// ---------------------------------------------------------------- K1c: values
// v_ws[h][b][t][e] = Xb[b,t,:] . W_V[t,:,:]  (per-token GEMM, streams W_V once)
__global__ void __launch_bounds__(512)
k1c_v(const u16* __restrict__ Xb, const float* __restrict__ WV, u16* __restrict__ v_ws){
  __shared__ u16 lds[128*256];   // 65536 B
  int t = blockIdx.x;
  int tid = threadIdx.x;
  int d = tid >> 1, esub = (tid & 1)*64;
  int lane = tid & 63, wv = tid >> 6;
  int q_l = lane >> 4, c_l = lane & 15;
  short8 afrag[8];
  #pragma unroll
  for (int kk = 0; kk < 8; ++kk)
    afrag[kk] = *(const short8*)&Xb[((size_t)c_l*T_ + t)*D_ + kk*32 + q_l*8];
  for (int eh = 0; eh < 2; ++eh){
    #pragma unroll 1
    for (int i = 0; i < 8; ++i){
      int el0 = esub + 8*i;
      int eg0 = eh*128 + el0;
      const float* p = &WV[((size_t)t*D_ + d)*HE_ + eg0];
      float4 m0 = *(const float4*)p;
      float4 m1 = *(const float4*)(p + 4);
      float v[8] = {m0.x,m0.y,m0.z,m0.w,m1.x,m1.y,m1.z,m1.w};
      #pragma unroll
      for (int jj = 0; jj < 8; ++jj){
        int el = el0 + jj;
        lds[el*256 + (((d>>3) ^ (el&31))<<3) + (d&7)] = f2bf(v[jj]);
      }
    }
    __syncthreads();
    floatx4 acc = {0,0,0,0};
    int el = wv*16 + c_l;
    #pragma unroll
    for (int kk = 0; kk < 8; ++kk){
      int c = kk*4 + q_l;
      short8 bfr = *(const short8*)&lds[el*256 + ((c ^ (el&31))<<3)];
      acc = __builtin_amdgcn_mfma_f32_16x16x32_bf16(afrag[kk], bfr, acc, 0, 0, 0);
    }
    int e_full = eh*128 + wv*16 + c_l;
    #pragma unroll
    for (int r = 0; r < 4; ++r){
      int b = q_l*4 + r;
      v_ws[(((size_t)(e_full >> 5)*B_ + b)*T_ + t)*E_ + (e_full & 31)] = f2bf(acc[r]);
    }
    __syncthreads();
  }
}

// ---------------------------------------------------------------- K2a: att
__global__ void __launch_bounds__(256)
k2a_att(const u16* __restrict__ q_ws, const u16* __restrict__ k_ws,
        const u16* __restrict__ lA, const u16* __restrict__ oml,
        u16* __restrict__ Mc, int hb0){
  int tt = blockIdx.x;       // 0..7  (t-tile of 64)
  int hbl = blockIdx.y;
  int hb = hb0 + hbl;
  int tid = threadIdx.x;
  int lane = tid & 63, wv = tid >> 6;
  int q_l = lane >> 4, c_l = lane & 15;
  int t0 = tt*64 + wv*16;
  const u16* qb = q_ws + (size_t)hb*T_*E_;
  const u16* kb = k_ws + (size_t)hb*T_*E_;
  short8 af = *(const short8*)&qb[(t0 + c_l)*E_ + q_l*8];
  floatx4 acc[32];
  #pragma unroll
  for (int st = 0; st < 32; ++st){
    short8 bfr = *(const short8*)&kb[(st*16 + c_l)*E_ + q_l*8];
    floatx4 z = {0,0,0,0};
    acc[st] = __builtin_amdgcn_mfma_f32_16x16x32_bf16(af, bfr, z, 0, 0, 0);
  }
  #pragma unroll
  for (int r = 0; r < 4; ++r){
    float mx = -1e30f;
    #pragma unroll
    for (int st = 0; st < 32; ++st) mx = fmaxf(mx, acc[st][r]);
    mx = fmaxf(mx, __shfl_xor(mx, 1)); mx = fmaxf(mx, __shfl_xor(mx, 2));
    mx = fmaxf(mx, __shfl_xor(mx, 4)); mx = fmaxf(mx, __shfl_xor(mx, 8));
    float sum = 0.f;
    #pragma unroll
    for (int st = 0; st < 32; ++st){ float e = __expf(acc[st][r] - mx); acc[st][r] = e; sum += e; }
    sum += __shfl_xor(sum, 1); sum += __shfl_xor(sum, 2);
    sum += __shfl_xor(sum, 4); sum += __shfl_xor(sum, 8);
    float inv = 1.0f / sum;
    #pragma unroll
    for (int st = 0; st < 32; ++st) acc[st][r] *= inv;
  }
  size_t ob = (size_t)hbl*T_*T_;
  #pragma unroll 1
  for (int st = 0; st < 32; ++st){
    #pragma unroll
    for (int r = 0; r < 4; ++r){
      int t = t0 + q_l*4 + r;
      int s = st*16 + c_l;
      float la = bflo((uint32_t)lA[t*T_ + s]);
      float om = bflo((uint32_t)oml[t*T_ + s]);
      Mc[ob + (size_t)t*T_ + s] = f2bf(la + om*acc[st][r]);
    }
  }
}

// ---------------------------------------------------------------- K2b: M
// In-place: M = exp(0.5*(att + att^T)), triangular 64x64 tile pairs.
__global__ void __launch_bounds__(256)
k2b_sym(u16* __restrict__ Mc){
  __shared__ u16 tA[64][65], tB[64][65];
  int p = blockIdx.x, I = 0;           // p in [0,36): (I,J) with I<=J
  while (p >= 8 - I){ p -= 8 - I; ++I; }
  int J = I + p;
  int hbl = blockIdx.y;
  size_t base = (size_t)hbl*T_*T_;
  int tid = threadIdx.x;
  #pragma unroll
  for (int i = 0; i < 16; ++i){
    int idx = tid + 256*i;
    int rr = idx >> 6, cc = idx & 63;
    tA[rr][cc] = Mc[base + (size_t)(I*64 + rr)*T_ + J*64 + cc];
    tB[rr][cc] = Mc[base + (size_t)(J*64 + rr)*T_ + I*64 + cc];
  }
  __syncthreads();
  #pragma unroll
  for (int i = 0; i < 16; ++i){
    int idx = tid + 256*i;
    int rr = idx >> 6, cc = idx & 63;
    float a = bflo((uint32_t)tA[rr][cc]);
    float b = bflo((uint32_t)tB[cc][rr]);
    Mc[base + (size_t)(I*64 + rr)*T_ + J*64 + cc] = f2bf(__expf(0.5f*(a + b)));
  }
  if (I != J){
    #pragma unroll
    for (int i = 0; i < 16; ++i){
      int idx = tid + 256*i;
      int rr = idx >> 6, cc = idx & 63;
      float a = bflo((uint32_t)tB[rr][cc]);
      float b = bflo((uint32_t)tA[cc][rr]);
      Mc[base + (size_t)(J*64 + rr)*T_ + I*64 + cc] = f2bf(__expf(0.5f*(a + b)));
    }
  }
}

// ---------------------------------------------------------------- K3: sinkhorn
// r = 1/(M c); c = 1/(M r), M symmetric.
// R7: 1024 threads/block (16 waves -> 4 waves/SIMD), half-row per thread:
// thread i owns row r=i&511, cols [h*256, h*256+256), h=i>>9.
// 92 dwords (184 cols) in registers + 36 dwords (72 cols) in LDS.
// __launch_bounds__(1024,4) -> 128-VGPR cap, demand ~115 -> no spill
// (R6 failure: VGPR_Count=256 vs ~390 needed -> spill-thrashed all 40 iters).
// Dynamic LDS 153600 B -> 1 block/CU.
#define K3_NREG 92
#define K3_NLDS 36
#define K3_LDS (K3_NLDS*1024*4 + 512*4 + 1024*4)   // 153600 B
__global__ void __launch_bounds__(1024, 4)
k3_sinkhorn(const u16* __restrict__ Mc, float* __restrict__ r_ws, float* __restrict__ c_ws,
            int hb0){
  extern __shared__ char dynsmem[];
  uint32_t* mlds = (uint32_t*)dynsmem;                       // [36][1024]
  float* vbuf    = (float*)(dynsmem + (size_t)K3_NLDS*1024*4); // [512]
  float* partial = vbuf + 512;                               // [1024]
  int hbl = blockIdx.x;
  int i = threadIdx.x;                                       // 0..1023
  int r = i & 511, h = i >> 9;
  int ch0 = h << 8;                                          // col base
  const uint4* rp = (const uint4*)(Mc + ((size_t)hbl*T_ + r)*T_ + ch0);
  uint32_t m[K3_NREG];
  #pragma unroll
  for (int j = 0; j < K3_NREG/4; ++j){                       // 23 x 16B
    uint4 v = rp[j];
    m[4*j] = v.x; m[4*j+1] = v.y; m[4*j+2] = v.z; m[4*j+3] = v.w;
  }
  #pragma unroll
  for (int j = 0; j < K3_NLDS/4; ++j){                       // 9 x 16B
    uint4 v = rp[K3_NREG/4 + j];
    mlds[(4*j + 0)*1024 + i] = v.x;
    mlds[(4*j + 1)*1024 + i] = v.y;
    mlds[(4*j + 2)*1024 + i] = v.z;
    mlds[(4*j + 3)*1024 + i] = v.w;
  }
  if (h == 0) vbuf[r] = 1.0f;
  __syncthreads();
  float lr = 0.f, lc = 1.0f;
  #pragma unroll 1
  for (int p = 0; p < 40; ++p){
    float a0 = 0.f, a1 = 0.f, a2 = 0.f, a3 = 0.f;
    #pragma unroll
    for (int j = 0; j < K3_NREG; j += 2){
      float4 w = *(const float4*)&vbuf[ch0 + 2*j];           // wave-uniform bcast
      uint32_t x0 = m[j], x1 = m[j+1];
      a0 += bflo(x0)*w.x; a1 += bfhi(x0)*w.y;
      a2 += bflo(x1)*w.z; a3 += bfhi(x1)*w.w;
    }
    #pragma unroll
    for (int j = 0; j < K3_NLDS; j += 2){
      float4 w = *(const float4*)&vbuf[ch0 + 2*K3_NREG + 2*j]; // bcast
      uint32_t x0 = mlds[j*1024 + i], x1 = mlds[(j+1)*1024 + i];
      a0 += bflo(x0)*w.x; a1 += bfhi(x0)*w.y;
      a2 += bflo(x1)*w.z; a3 += bfhi(x1)*w.w;
    }
    partial[i] = (a0 + a1) + (a2 + a3);
    __syncthreads();
    float nv = 1.0f / (partial[r] + partial[r + 512]);
    if (p & 1) lc = nv; else lr = nv;
    if (h == 0) vbuf[r] = nv;
    __syncthreads();
  }
  if (h == 0){
    int hb = hb0 + hbl;
    r_ws[hb*T_ + r] = lr;
    c_ws[hb*T_ + r] = lc;
  }
}

// ---------------------------------------------------------------- K4: out
// out[b,t,h*32+e] = r[t] * sum_s M[t,s] * (c[s]*V[s,e])   (fp32 out)
#define K4_VS 520
__global__ void __launch_bounds__(256)
k4_out(const u16* __restrict__ Mc, const u16* __restrict__ v_ws,
       const float* __restrict__ r_ws, const float* __restrict__ c_ws,
       float* __restrict__ out, int hb0){
  __shared__ u16 vt[32*K4_VS + 8];   // 33296 B
  int th = blockIdx.x;       // t-half
  int hbl = blockIdx.y;
  int hb = hb0 + hbl;
  int h = hb >> 4, b = hb & 15;
  int tid = threadIdx.x;
  const u16* vb = v_ws + (size_t)hb*T_*E_;
  const float* cvec = c_ws + hb*T_;
  #pragma unroll
  for (int rr = 0; rr < 2; ++rr){
    int s = tid + rr*256;
    float cs = cvec[s];
    #pragma unroll
    for (int j4 = 0; j4 < 4; ++j4){
      uint4 v = *(const uint4*)&vb[s*E_ + j4*8];
      uint32_t vv[4] = {v.x,v.y,v.z,v.w};
      #pragma unroll
      for (int j = 0; j < 4; ++j){
        vt[(j4*8 + 2*j    )*K4_VS + s] = f2bf(bflo(vv[j])*cs);
        vt[(j4*8 + 2*j + 1)*K4_VS + s] = f2bf(bfhi(vv[j])*cs);
      }
    }
  }
  __syncthreads();
  int lane = tid & 63, wv = tid >> 6;
  int q_l = lane >> 4, c_l = lane & 15;
  const float* rvec = r_ws + hb*T_;
  const u16* mrow = Mc + (size_t)hbl*T_*T_;
  #pragma unroll 1
  for (int mt = 0; mt < 4; ++mt){
    int t0 = th*256 + (wv*4 + mt)*16;
    floatx4 acc0 = {0,0,0,0}, acc1 = {0,0,0,0};
    #pragma unroll
    for (int kk = 0; kk < 16; ++kk){
      int k0 = kk*32;
      short8 af = *(const short8*)&mrow[(size_t)(t0 + c_l)*T_ + k0 + q_l*8];
      short8 b0 = *(const short8*)&vt[(0  + c_l)*K4_VS + k0 + q_l*8];
      short8 b1 = *(const short8*)&vt[(16 + c_l)*K4_VS + k0 + q_l*8];
      acc0 = __builtin_amdgcn_mfma_f32_16x16x32_bf16(af, b0, acc0, 0, 0, 0);
      acc1 = __builtin_amdgcn_mfma_f32_16x16x32_bf16(af, b1, acc1, 0, 0, 0);
    }
    #pragma unroll
    for (int r = 0; r < 4; ++r){
      int t = t0 + q_l*4 + r;
      float rt = rvec[t];
      out[((size_t)(b*T_ + t))*HE_ + h*E_ + 0  + c_l] = acc0[r]*rt;
      out[((size_t)(b*T_ + t))*HE_ + h*E_ + 16 + c_l] = acc1[r]*rt;
    }
  }
}

// ---------------------------------------------------------------- launch
extern "C" void kernel_launch(void* const* d_in, const int* in_sizes, int n_in,
                              void* d_out, int out_size, void* d_ws, size_t ws_size,
                              hipStream_t stream){
  const float* X  = (const float*)d_in[0];
  const float* te = (const float*)d_in[1];
  const float* Wq = (const float*)d_in[2];
  const float* Wk = (const float*)d_in[3];
  const float* Qb = (const float*)d_in[4];
  const float* Kb = (const float*)d_in[5];
  const float* WV = (const float*)d_in[6];
  const float* Al = (const float*)d_in[7];
  const float* Ll = (const float*)d_in[8];
  float* out = (float*)d_out;
  (void)in_sizes; (void)n_in; (void)out_size;

  char* w = (char*)d_ws;
  float* qw   = (float*)w;  w += 16384;
  float* kw   = (float*)w;  w += 16384;
  u16* lA     = (u16*)w;    w += 524288;
  u16* oml    = (u16*)w;    w += 524288;
  u16* q_ws   = (u16*)w;    w += 4194304;
  u16* k_ws   = (u16*)w;    w += 4194304;
  u16* v_ws   = (u16*)w;    w += 4194304;
  float* r_ws = (float*)w;  w += 262144;
  float* c_ws = (float*)w;  w += 262144;
  // slab (aliased): [Xb 4.19M][QbT 1.05M][KbT 1.05M][Y 33.55M] then reused as Mc
  u16* slab = (u16*)w;
  u16* Xb  = slab;
  u16* QbT = slab + 2097152;
  u16* KbT = slab + 2621440;
  u16* Y   = slab + 3145728;
  u16* Mc  = slab;
  size_t fixed = (size_t)(w - (char*)d_ws);
  size_t slabsz = (ws_size > fixed) ? (ws_size - fixed) : 0;
  int nhb = HB_;
  while (nhb > 1 && (size_t)nhb*T_*T_*2 > slabsz) nhb >>= 1;

  // >64KB dynamic-LDS opt-in for k3 (host-side, idempotent, capture-safe)
  hipFuncSetAttribute((const void*)k3_sinkhorn,
                      hipFuncAttributeMaxDynamicSharedMemorySize, K3_LDS);

  kcvt_x  <<<2048, 256, 0, stream>>>(X, Xb);
  kT_basis<<<dim3(16, 16), 256, 0, stream>>>(Qb, Kb, QbT, KbT);
  k0_meta <<<T_, 64, 0, stream>>>(te, Wq, Wk, qw, kw);
  k_pre   <<<64, 256, 0, stream>>>(Al, Ll, lA, oml);
  k1c_v   <<<T_, 512, 0, stream>>>(Xb, WV, v_ws);
  k1a_gemm<<<dim3(64, 2, 8), 256, 0, stream>>>(Xb, QbT, Y);
  k1b_mix <<<512, 256, 0, stream>>>(Y, qw, q_ws);
  k1a_gemm<<<dim3(64, 2, 8), 256, 0, stream>>>(Xb, KbT, Y);
  k1b_mix <<<512, 256, 0, stream>>>(Y, kw, k_ws);
  for (int hb0 = 0; hb0 < HB_; hb0 += nhb){
    k2a_att    <<<dim3(8, nhb), 256, 0, stream>>>(q_ws, k_ws, lA, oml, Mc, hb0);
    k2b_sym    <<<dim3(36, nhb), 256, 0, stream>>>(Mc);
    k3_sinkhorn<<<nhb, 1024, K3_LDS, stream>>>(Mc, r_ws, c_ws, hb0);
    k4_out     <<<dim3(2, nhb), 256, 0, stream>>>(Mc, v_ws, r_ws, c_ws, out, hb0);
  }
}